// Round 21
// baseline (157.426 us; speedup 1.0000x reference)
//
#include <hip/hip_runtime.h>
#include <hip/hip_bf16.h>

using bfrag  = __attribute__((ext_vector_type(8))) __bf16;
using f32x4  = __attribute__((ext_vector_type(4))) float;
using f32x16 = __attribute__((ext_vector_type(16))) float;
using v4u    = __attribute__((ext_vector_type(4))) unsigned int;
using v2u    = __attribute__((ext_vector_type(2))) unsigned int;

__device__ __forceinline__ ushort f2bf(float f) {
    union { float f; unsigned u; } c; c.f = f;
    return (ushort)((c.u + 0x7fffu + ((c.u >> 16) & 1u)) >> 16);
}

__device__ __forceinline__ float bf2f(ushort u) {
    union { unsigned u; float f; } c; c.u = (unsigned)u << 16; return c.f;
}

__device__ __forceinline__ unsigned pack_bf16x2(float lo, float hi) {
    union { __hip_bfloat162 h; unsigned u; } c;
    c.h = __float22bfloat162_rn(make_float2(lo, hi));   // lo -> low ushort, hi -> high
    return c.u;
}

__device__ __forceinline__ void gld_lds16(const ushort* g, ushort* l) {
    __builtin_amdgcn_global_load_lds(
        (const __attribute__((address_space(1))) void*)g,
        (__attribute__((address_space(3))) void*)l, 16, 0, 0);
}

__device__ __forceinline__ f32x16 mfma32(bfrag a, bfrag b, f32x16 c) {
    return __builtin_amdgcn_mfma_f32_32x32x16_bf16(a, b, c, 0, 0, 0);
}

// ---------------- conversions, one dispatch ----------------
// z = 0..2: fp32 [1024][1024] -> bf16 transposed (Wq, Wv, Wo)
// z = 3..10: q,v fp32 -> bf16 flat (2M float4 total)

__global__ void cvt_all(const float* __restrict__ s0, ushort* __restrict__ d0,
                        const float* __restrict__ s1, ushort* __restrict__ d1,
                        const float* __restrict__ s2, ushort* __restrict__ d2,
                        const float* __restrict__ q, ushort* __restrict__ qbf,
                        const float* __restrict__ v, ushort* __restrict__ vbf) {
    const int z = blockIdx.z;
    if (z < 3) {
        __shared__ float t[32][33];
        const float* src = z == 0 ? s0 : z == 1 ? s1 : s2;
        ushort* dst = z == 0 ? d0 : z == 1 ? d1 : d2;
        const int tx = threadIdx.x, ty = threadIdx.y;
        const int c0 = blockIdx.x * 32, r0 = blockIdx.y * 32;
        for (int i = ty; i < 32; i += 8) t[i][tx] = src[(size_t)(r0 + i) * 1024 + c0 + tx];
        __syncthreads();
        for (int i = ty; i < 32; i += 8) dst[(size_t)(c0 + i) * 1024 + r0 + tx] = f2bf(t[tx][i]);
    } else {
        const int tid = threadIdx.y * 32 + threadIdx.x;
        int i = ((z - 3) * 1024 + blockIdx.y * 32 + blockIdx.x) * 256 + tid;
        const float* s; ushort* d;
        if (i < 1048576) { s = q; d = qbf; } else { s = v; d = vbf; i -= 1048576; }
        float4 f = ((const float4*)s)[i];
        ((ushort4*)d)[i] = make_ushort4(f2bf(f.x), f2bf(f.y), f2bf(f.z), f2bf(f.w));
    }
}

// ---------------- gemm_qv: 64x128 tile, bf16 A via gld_lds, fused VPT epilogue ----------------

__global__ __launch_bounds__(256, 3) void gemm_qv(
    const ushort* __restrict__ Aq, const ushort* __restrict__ Wq, const float* __restrict__ bq, ushort* __restrict__ Cq,
    const ushort* __restrict__ Av, const ushort* __restrict__ Wv, const float* __restrict__ bv, ushort* __restrict__ Cv,
    ushort* __restrict__ VPT, float qscale)
{
    __shared__ ushort SM[12288];               // As[2] at 0/2048, Bs[2] at 4096/8192; reused as T[64][129]
    const int z = blockIdx.z;
    const ushort* A  = z ? Av : Aq;
    const ushort* Bt = z ? Wv : Wq;
    const float* bias = z ? bv : bq;
    ushort* Cout = z ? Cv : Cq;
    const float scale = z ? 1.0f : qscale;

    const int tid = threadIdx.x;
    const int lane = tid & 63, w = tid >> 6;
    const int l15 = lane & 15, lg = lane >> 4;
    const int wr = w >> 1, wc = w & 1;
    const int bM = blockIdx.y, bN = blockIdx.x;

    const ushort* Ag = A + (size_t)bM * 64 * 1024;
    const ushort* Bg = Bt + (size_t)bN * 128 * 1024;
    const int ar = tid >> 2;
    const int cc = (tid & 3) * 8;

    auto STAGE = [&](int buf, int kt) {
        const int kk = kt * 32;
        gld_lds16(Ag + (size_t)ar * 1024 + kk + cc, &SM[buf * 2048 + tid * 8]);
#pragma unroll
        for (int i = 0; i < 2; ++i)
            gld_lds16(Bg + (size_t)(ar + i * 64) * 1024 + kk + cc,
                      &SM[4096 + buf * 4096 + (tid + i * 256) * 8]);
    };

    f32x4 acc[2][4];
#pragma unroll
    for (int m = 0; m < 2; ++m)
#pragma unroll
        for (int n = 0; n < 4; ++n) acc[m][n] = (f32x4){0.f, 0.f, 0.f, 0.f};

    STAGE(0, 0);
    __syncthreads();
    int cur = 0;
    for (int kt = 0; kt < 32; ++kt) {
        if (kt < 31) STAGE(cur ^ 1, kt + 1);
        bfrag aF[2], bF[4];
#pragma unroll
        for (int m = 0; m < 2; ++m)
            aF[m] = *(const bfrag*)&SM[cur * 2048 + (wr * 32 + m * 16 + l15) * 32 + lg * 8];
#pragma unroll
        for (int n = 0; n < 4; ++n)
            bF[n] = *(const bfrag*)&SM[4096 + cur * 4096 + (wc * 64 + n * 16 + l15) * 32 + lg * 8];
        __builtin_amdgcn_s_setprio(1);
#pragma unroll
        for (int m = 0; m < 2; ++m)
#pragma unroll
            for (int n = 0; n < 4; ++n)
                acc[m][n] = __builtin_amdgcn_mfma_f32_16x16x32_bf16(aF[m], bF[n], acc[m][n], 0, 0, 0);
        __builtin_amdgcn_s_setprio(0);
        if (kt < 31) {
            __syncthreads();
            cur ^= 1;
        }
    }

    __syncthreads();                 // all waves done with LDS fragments; SM reusable as T
#pragma unroll
    for (int m = 0; m < 2; ++m)
#pragma unroll
        for (int n = 0; n < 4; ++n) {
            const int lcol = wc * 64 + n * 16 + l15;
            const int gcol = bN * 128 + lcol;
            const float bv_ = bias[gcol];
#pragma unroll
            for (int j = 0; j < 4; ++j) {
                const int lrow = wr * 32 + m * 16 + lg * 4 + j;
                const float val = (acc[m][n][j] + bv_) * scale;
                const ushort hv = f2bf(val);
                Cout[(size_t)(bM * 64 + lrow) * 1024 + gcol] = hv;
                if (z) SM[lrow * 129 + lcol] = hv;
            }
        }

    if (z) {                         // fused VPT transpose (sigma on s within 16-blocks)
        __syncthreads();
        const int b_ = (bM * 64) >> 11;
        const int s0 = (bM * 64) & 2047;
        const int h0 = bN * 2;
#pragma unroll
        for (int i = 0; i < 4; ++i) {
            const int c2 = i * 256 + tid;
            const int d128 = c2 >> 3;
            const int sb = (c2 & 7) * 8;
            union { ushort s[8]; v4u v; } tmp;
#pragma unroll
            for (int jj = 0; jj < 8; ++jj) {
                const int sl = sb + jj;
                const int js = (sl & ~15) | (sl & 3) | ((sl >> 1) & 4) | ((sl << 1) & 8);
                tmp.s[jj] = SM[js * 129 + d128];
            }
            ushort* dst = VPT + ((size_t)((b_ * 16 + h0 + (d128 >> 6)) * 64 + (d128 & 63))) * 2048 + s0 + sb;
            *(v4u*)dst = tmp.v;
        }
    }
}

// ---------------- gemm_o<NSPLIT>: out = normalize(sum Opart[s]) @ WoT^T + bo ----------------

template<int NSPLIT>
__global__ __launch_bounds__(256, 3) void gemm_o(
    const ushort* __restrict__ Op, const float* __restrict__ Lp,
    const ushort* __restrict__ Bt, const float* __restrict__ bias,
    float* __restrict__ out)
{
    __shared__ ushort As[2][2048];
    __shared__ ushort Bs[2][4096];
    const int tid = threadIdx.x;
    const int lane = tid & 63, w = tid >> 6;
    const int l15 = lane & 15, lg = lane >> 4;
    const int wr = w >> 1, wc = w & 1;
    const int bM = blockIdx.y, bN = blockIdx.x;

    const ushort* Bg = Bt + (size_t)bN * 128 * 1024;
    const int ar = tid >> 2;
    const int cc = (tid & 3) * 8;
    const int grow = bM * 64 + ar;
    const int b_ = grow >> 11, s_ = grow & 2047;

    float a8[8]; float linv;
    auto LOAD_A = [&](int kt) {
        const int col = kt * 32 + cc;
        const int li = (b_ * 16 + (col >> 6)) * 2048 + s_;
        float l = 0.f;
#pragma unroll
        for (int j = 0; j < 8; ++j) a8[j] = 0.f;
#pragma unroll
        for (int s = 0; s < NSPLIT; ++s) {
            l += Lp[s * 65536 + li];
            v4u r = *(const v4u*)(Op + (size_t)s * 4194304 + (size_t)grow * 1024 + col);
#pragma unroll
            for (int wd = 0; wd < 4; ++wd) {
                a8[2 * wd]     += bf2f((ushort)(r[wd] & 0xffff));
                a8[2 * wd + 1] += bf2f((ushort)(r[wd] >> 16));
            }
        }
        linv = 1.0f / l;
    };
    auto WRITE_A = [&](int buf) {
        v4u o;
#pragma unroll
        for (int wd = 0; wd < 4; ++wd)
            o[wd] = pack_bf16x2(a8[2 * wd] * linv, a8[2 * wd + 1] * linv);
        *(v4u*)&As[buf][tid * 8] = o;
    };
    auto STAGE_B = [&](int buf, int kt) {
        const int kk = kt * 32;
#pragma unroll
        for (int i = 0; i < 2; ++i)
            gld_lds16(Bg + (size_t)(ar + i * 64) * 1024 + kk + cc, &Bs[buf][(tid + i * 256) * 8]);
    };

    f32x4 acc[2][4];
#pragma unroll
    for (int m = 0; m < 2; ++m)
#pragma unroll
        for (int n = 0; n < 4; ++n) acc[m][n] = (f32x4){0.f, 0.f, 0.f, 0.f};

    LOAD_A(0);
    STAGE_B(0, 0);
    WRITE_A(0);
    __syncthreads();
    int cur = 0;
    for (int kt = 0; kt < 32; ++kt) {
        if (kt < 31) {
            LOAD_A(kt + 1);
            STAGE_B(cur ^ 1, kt + 1);
        }
        bfrag aF[2], bF[4];
#pragma unroll
        for (int m = 0; m < 2; ++m) aF[m] = *(const bfrag*)&As[cur][(wr * 32 + m * 16 + l15) * 32 + lg * 8];
#pragma unroll
        for (int n = 0; n < 4; ++n) bF[n] = *(const bfrag*)&Bs[cur][(wc * 64 + n * 16 + l15) * 32 + lg * 8];
        __builtin_amdgcn_s_setprio(1);
#pragma unroll
        for (int m = 0; m < 2; ++m)
#pragma unroll
            for (int n = 0; n < 4; ++n)
                acc[m][n] = __builtin_amdgcn_mfma_f32_16x16x32_bf16(aF[m], bF[n], acc[m][n], 0, 0, 0);
        __builtin_amdgcn_s_setprio(0);
        if (kt < 31) {
            WRITE_A(cur ^ 1);
            __syncthreads();
            cur ^= 1;
        }
    }

#pragma unroll
    for (int m = 0; m < 2; ++m)
#pragma unroll
        for (int n = 0; n < 4; ++n) {
            const int gcol = bN * 128 + wc * 64 + n * 16 + l15;
            const float bv_ = bias[gcol];
#pragma unroll
            for (int j = 0; j < 4; ++j) {
                const int gr = bM * 64 + wr * 32 + m * 16 + lg * 4 + j;
                out[(size_t)gr * 1024 + gcol] = acc[m][n][j] + bv_;
            }
        }
}

// ---------------- flash attention<NT>: r16 structure, NT kv-tiles per block ----------------
// 4-wave blocks, q=64/wave, fixed-offset softmax, VALU l-sum.
// NT=16 -> split-KV x2 (proven 52.7us). NT=8 -> split-KV x4: 1024 blocks = 4/CU
// co-resident = 16 waves/CU (the one occupancy config never tested; r8's attempt
// died to a launch-bounds VGPR cap, not the idea). LDS 32KB x4 = 128KB <= 160 OK.

template<int NT>
__global__ __launch_bounds__(256, 2) void attn_kernel(
    const ushort* __restrict__ QP, const ushort* __restrict__ VP,
    const ushort* __restrict__ VPT, ushort* __restrict__ Opart, float* __restrict__ Lpart)
{
    __shared__ ushort Ks[2][4096];
    __shared__ ushort Vs[2][4096];
    const int tid = threadIdx.x;
    const int w = tid >> 6, lane = tid & 63;
    const int l31 = lane & 31, hi = lane >> 5;
    const int bh = blockIdx.x, qt = blockIdx.y, half = blockIdx.z;
    const int b = bh >> 4, h = bh & 15;
    const int qrow0 = qt * 256 + w * 64;
    const int k0 = half * NT;

    const int sr = lane >> 3;
    const int sc = ((lane & 7) ^ sr) * 8;
    const ushort* Kg = VP + (size_t)(b * 2048) * 1024 + h * 64 + sc;
    const ushort* Vg = VPT + (size_t)bh * 131072 + sc;

    auto STAGE = [&](int slot, int kt) {
#pragma unroll
        for (int i = 0; i < 2; ++i) {
            const int kb = w * 2 + i;
            const int r = kb * 8 + sr;
            gld_lds16(Kg + (size_t)(kt * 64 + r) * 1024, &Ks[slot][kb * 512]);
            gld_lds16(Vg + (size_t)r * 2048 + kt * 64, &Vs[slot][kb * 512]);
        }
    };

    const ushort* Qp = QP + ((size_t)(b * 2048 + qrow0 + l31)) * 1024 + h * 64 + hi * 8;
    bfrag qA[4], qBt[4];
#pragma unroll
    for (int ds = 0; ds < 4; ++ds) {
        qA[ds]  = *(const bfrag*)(Qp + ds * 16);
        qBt[ds] = *(const bfrag*)(Qp + 32 * 1024 + ds * 16);
    }

    f32x16 OA0, OA1, OB0, OB1;
#pragma unroll
    for (int r = 0; r < 16; ++r) { OA0[r] = 0.f; OA1[r] = 0.f; OB0[r] = 0.f; OB1[r] = 0.f; }
    float lrunA = 0.f, lrunB = 0.f;

    const int swz = (l31 & 7) << 4;
    const int cA = hi * 16;

    STAGE(0, k0);
    __syncthreads();

    auto SOFTMAX = [&](f32x16& S0, f32x16& S1, bfrag (&pB)[4], float& lrun) {
        float p[32];
#pragma unroll
        for (int r = 0; r < 16; ++r) {
            p[r]      = __builtin_amdgcn_exp2f(S0[r]);
            p[16 + r] = __builtin_amdgcn_exp2f(S1[r]);
        }
        float s8[8];
#pragma unroll
        for (int i = 0; i < 8; ++i) s8[i] = (p[i] + p[i + 8]) + (p[i + 16] + p[i + 24]);
        lrun += ((s8[0] + s8[1]) + (s8[2] + s8[3])) + ((s8[4] + s8[5]) + (s8[6] + s8[7]));
#pragma unroll
        for (int c = 0; c < 4; ++c) {
            union { v4u u; bfrag f; } cv;
#pragma unroll
            for (int wd = 0; wd < 4; ++wd)
                cv.u[wd] = pack_bf16x2(p[8 * c + 2 * wd], p[8 * c + 2 * wd + 1]);
            pB[c] = cv.f;
        }
    };

#pragma unroll 1
    for (int t = 0; t < NT; ++t) {
        if (t > 0) __syncthreads();
        if (t + 1 < NT) STAGE((t + 1) & 1, k0 + t + 1);
        const ushort* Kb_ = Ks[t & 1];
        const ushort* Vb_ = Vs[t & 1];

        bfrag k0f[4], k1f[4];
#pragma unroll
        for (int ds = 0; ds < 4; ++ds) {
            k0f[ds] = *(const bfrag*)&Kb_[(l31 * 128 + ((ds * 32 + cA) ^ swz)) >> 1];
            k1f[ds] = *(const bfrag*)&Kb_[((l31 + 32) * 128 + ((ds * 32 + cA) ^ swz)) >> 1];
        }
        f32x16 SA0, SA1, SB0, SB1;
#pragma unroll
        for (int r = 0; r < 16; ++r) { SA0[r] = -16.f; SA1[r] = -16.f; SB0[r] = -16.f; SB1[r] = -16.f; }
        __builtin_amdgcn_s_setprio(1);
#pragma unroll
        for (int ds = 0; ds < 4; ++ds) {
            SA0 = mfma32(k0f[ds], qA[ds], SA0);
            SA1 = mfma32(k1f[ds], qA[ds], SA1);
            SB0 = mfma32(k0f[ds], qBt[ds], SB0);
            SB1 = mfma32(k1f[ds], qBt[ds], SB1);
        }
        __builtin_amdgcn_s_setprio(0);

        bfrag pBA[4], pBB[4];
        SOFTMAX(SA0, SA1, pBA, lrunA);
        SOFTMAX(SB0, SB1, pBB, lrunB);

        bfrag vF0[4], vF1[4];
#pragma unroll
        for (int c = 0; c < 4; ++c) {
            vF0[c] = *(const bfrag*)&Vb_[(l31 * 128 + ((c * 32 + cA) ^ swz)) >> 1];
            vF1[c] = *(const bfrag*)&Vb_[((l31 + 32) * 128 + ((c * 32 + cA) ^ swz)) >> 1];
        }
        __builtin_amdgcn_s_setprio(1);
#pragma unroll
        for (int c = 0; c < 4; ++c) {
            OA0 = mfma32(vF0[c], pBA[c], OA0);
            OA1 = mfma32(vF1[c], pBA[c], OA1);
            OB0 = mfma32(vF0[c], pBB[c], OB0);
            OB1 = mfma32(vF1[c], pBB[c], OB1);
        }
        __builtin_amdgcn_s_setprio(0);
    }

    lrunA += __shfl_xor(lrunA, 32);
    lrunB += __shfl_xor(lrunB, 32);
    ushort* AoA = Opart + (size_t)half * 4194304
                + (size_t)(b * 2048 + qrow0 + l31) * 1024 + h * 64 + hi * 4;
    ushort* AoB = AoA + 32 * 1024;
#pragma unroll
    for (int t = 0; t < 2; ++t) {
#pragma unroll
        for (int g = 0; g < 4; ++g) {
            const float a0 = t ? OA1[4 * g + 0] : OA0[4 * g + 0];
            const float a1 = t ? OA1[4 * g + 1] : OA0[4 * g + 1];
            const float a2 = t ? OA1[4 * g + 2] : OA0[4 * g + 2];
            const float a3 = t ? OA1[4 * g + 3] : OA0[4 * g + 3];
            *(v2u*)(AoA + t * 32 + g * 8) = (v2u){pack_bf16x2(a0, a1), pack_bf16x2(a2, a3)};
            const float b0 = t ? OB1[4 * g + 0] : OB0[4 * g + 0];
            const float b1 = t ? OB1[4 * g + 1] : OB0[4 * g + 1];
            const float b2 = t ? OB1[4 * g + 2] : OB0[4 * g + 2];
            const float b3 = t ? OB1[4 * g + 3] : OB0[4 * g + 3];
            *(v2u*)(AoB + t * 32 + g * 8) = (v2u){pack_bf16x2(b0, b1), pack_bf16x2(b2, b3)};
        }
    }
    if (hi == 0) {
        Lpart[half * 65536 + bh * 2048 + qrow0 + l31] = lrunA;
        Lpart[half * 65536 + bh * 2048 + qrow0 + 32 + l31] = lrunB;
    }
}

// ---------------- launcher ----------------

extern "C" void kernel_launch(void* const* d_in, const int* in_sizes, int n_in,
                              void* d_out, int out_size, void* d_ws, size_t ws_size,
                              hipStream_t stream) {
    (void)in_sizes; (void)n_in; (void)out_size;
    const float* q  = (const float*)d_in[0];
    const float* v  = (const float*)d_in[2];
    const float* Wq = (const float*)d_in[3];
    const float* bq = (const float*)d_in[4];
    const float* Wv = (const float*)d_in[7];
    const float* bv = (const float*)d_in[8];
    const float* Wo = (const float*)d_in[9];
    const float* bo = (const float*)d_in[10];
    float* out = (float*)d_out;
    char* ws = (char*)d_ws;
    const size_t MB = 1ull << 20;
    const bool big = ws_size >= 59 * MB;    // split-KV x4 needs 59MB; else proven x2 layout

    // common early-phase buffers (dead before Opart is written)
    ushort* qbf = (ushort*)(ws + 0);         // 8MB
    ushort* vbf = (ushort*)(ws + 8 * MB);    // 8MB
    ushort* WqT = (ushort*)(ws + 16 * MB);   // 2MB
    ushort* WvT = (ushort*)(ws + 18 * MB);   // 2MB

    ushort *WoT, *QPb, *VPb, *VPT, *Opart; float* Lpart;
    if (big) {
        Opart = (ushort*)(ws + 0);           // [4][4096][1024] bf16 (32MB, overlays dead bufs)
        Lpart = (float*)(ws + 32 * MB);      // [4][32][2048] f32 (1MB)
        WoT   = (ushort*)(ws + 33 * MB);     // 2MB
        QPb   = (ushort*)(ws + 35 * MB);     // 8MB
        VPb   = (ushort*)(ws + 43 * MB);     // 8MB
        VPT   = (ushort*)(ws + 51 * MB);     // 8MB   (total 59MB)
    } else {
        Opart = (ushort*)(ws + 0);           // [2][4096][1024] bf16 (16MB)
        Lpart = (float*)(ws + 16 * MB);      // 0.5MB (overlays dead WqT)
        WoT   = (ushort*)(ws + 20 * MB);     // 2MB
        QPb   = (ushort*)(ws + 22 * MB);     // 8MB
        VPb   = (ushort*)(ws + 30 * MB);     // 8MB
        VPT   = (ushort*)(ws + 38 * MB);     // 8MB   (total 46MB, proven)
    }

    cvt_all<<<dim3(32, 32, 11), dim3(32, 8), 0, stream>>>(
        Wq, WqT, Wv, WvT, Wo, WoT, q, qbf, v, vbf);

    const float qscale = 0.125f * 1.44269504088896340736f;
    gemm_qv<<<dim3(8, 64, 2), 256, 0, stream>>>(qbf, WqT, bq, QPb,
                                                vbf, WvT, bv, VPb, VPT, qscale);
    if (big) {
        attn_kernel<8><<<dim3(32, 8, 4), 256, 0, stream>>>(QPb, VPb, VPT, Opart, Lpart);
        gemm_o<4><<<dim3(8, 64), 256, 0, stream>>>(Opart, Lpart, WoT, bo, out);
    } else {
        attn_kernel<16><<<dim3(32, 8, 2), 256, 0, stream>>>(QPb, VPb, VPT, Opart, Lpart);
        gemm_o<2><<<dim3(8, 64), 256, 0, stream>>>(Opart, Lpart, WoT, bo, out);
    }
}

// Round 22
// 126.361 us; speedup vs baseline: 1.2458x; 1.2458x over previous
//
#include <hip/hip_runtime.h>
#include <hip/hip_bf16.h>

using bfrag  = __attribute__((ext_vector_type(8))) __bf16;
using f32x4  = __attribute__((ext_vector_type(4))) float;
using f32x16 = __attribute__((ext_vector_type(16))) float;
using v4u    = __attribute__((ext_vector_type(4))) unsigned int;
using v2u    = __attribute__((ext_vector_type(2))) unsigned int;

__device__ __forceinline__ ushort f2bf(float f) {
    union { float f; unsigned u; } c; c.f = f;
    return (ushort)((c.u + 0x7fffu + ((c.u >> 16) & 1u)) >> 16);
}

__device__ __forceinline__ float bf2f(ushort u) {
    union { unsigned u; float f; } c; c.u = (unsigned)u << 16; return c.f;
}

__device__ __forceinline__ unsigned pack_bf16x2(float lo, float hi) {
    union { __hip_bfloat162 h; unsigned u; } c;
    c.h = __float22bfloat162_rn(make_float2(lo, hi));   // lo -> low ushort, hi -> high
    return c.u;
}

__device__ __forceinline__ void gld_lds16(const ushort* g, ushort* l) {
    __builtin_amdgcn_global_load_lds(
        (const __attribute__((address_space(1))) void*)g,
        (__attribute__((address_space(3))) void*)l, 16, 0, 0);
}

__device__ __forceinline__ f32x16 mfma32(bfrag a, bfrag b, f32x16 c) {
    return __builtin_amdgcn_mfma_f32_32x32x16_bf16(a, b, c, 0, 0, 0);
}

// ---------------- conversions, one dispatch ----------------

__global__ void cvt_all(const float* __restrict__ s0, ushort* __restrict__ d0,
                        const float* __restrict__ s1, ushort* __restrict__ d1,
                        const float* __restrict__ s2, ushort* __restrict__ d2,
                        const float* __restrict__ q, ushort* __restrict__ qbf,
                        const float* __restrict__ v, ushort* __restrict__ vbf) {
    const int z = blockIdx.z;
    if (z < 3) {
        __shared__ float t[32][33];
        const float* src = z == 0 ? s0 : z == 1 ? s1 : s2;
        ushort* dst = z == 0 ? d0 : z == 1 ? d1 : d2;
        const int tx = threadIdx.x, ty = threadIdx.y;
        const int c0 = blockIdx.x * 32, r0 = blockIdx.y * 32;
        for (int i = ty; i < 32; i += 8) t[i][tx] = src[(size_t)(r0 + i) * 1024 + c0 + tx];
        __syncthreads();
        for (int i = ty; i < 32; i += 8) dst[(size_t)(c0 + i) * 1024 + r0 + tx] = f2bf(t[tx][i]);
    } else {
        const int tid = threadIdx.y * 32 + threadIdx.x;
        int i = ((z - 3) * 1024 + blockIdx.y * 32 + blockIdx.x) * 256 + tid;
        const float* s; ushort* d;
        if (i < 1048576) { s = q; d = qbf; } else { s = v; d = vbf; i -= 1048576; }
        float4 f = ((const float4*)s)[i];
        ((ushort4*)d)[i] = make_ushort4(f2bf(f.x), f2bf(f.y), f2bf(f.z), f2bf(f.w));
    }
}

// ---------------- gemm_qv: 64x128 tile, bf16 A via gld_lds, fused VPT epilogue ----------------

__global__ __launch_bounds__(256, 3) void gemm_qv(
    const ushort* __restrict__ Aq, const ushort* __restrict__ Wq, const float* __restrict__ bq, ushort* __restrict__ Cq,
    const ushort* __restrict__ Av, const ushort* __restrict__ Wv, const float* __restrict__ bv, ushort* __restrict__ Cv,
    ushort* __restrict__ VPT, float qscale)
{
    __shared__ ushort SM[12288];
    const int z = blockIdx.z;
    const ushort* A  = z ? Av : Aq;
    const ushort* Bt = z ? Wv : Wq;
    const float* bias = z ? bv : bq;
    ushort* Cout = z ? Cv : Cq;
    const float scale = z ? 1.0f : qscale;

    const int tid = threadIdx.x;
    const int lane = tid & 63, w = tid >> 6;
    const int l15 = lane & 15, lg = lane >> 4;
    const int wr = w >> 1, wc = w & 1;
    const int bM = blockIdx.y, bN = blockIdx.x;

    const ushort* Ag = A + (size_t)bM * 64 * 1024;
    const ushort* Bg = Bt + (size_t)bN * 128 * 1024;
    const int ar = tid >> 2;
    const int cc = (tid & 3) * 8;

    auto STAGE = [&](int buf, int kt) {
        const int kk = kt * 32;
        gld_lds16(Ag + (size_t)ar * 1024 + kk + cc, &SM[buf * 2048 + tid * 8]);
#pragma unroll
        for (int i = 0; i < 2; ++i)
            gld_lds16(Bg + (size_t)(ar + i * 64) * 1024 + kk + cc,
                      &SM[4096 + buf * 4096 + (tid + i * 256) * 8]);
    };

    f32x4 acc[2][4];
#pragma unroll
    for (int m = 0; m < 2; ++m)
#pragma unroll
        for (int n = 0; n < 4; ++n) acc[m][n] = (f32x4){0.f, 0.f, 0.f, 0.f};

    STAGE(0, 0);
    __syncthreads();
    int cur = 0;
    for (int kt = 0; kt < 32; ++kt) {
        if (kt < 31) STAGE(cur ^ 1, kt + 1);
        bfrag aF[2], bF[4];
#pragma unroll
        for (int m = 0; m < 2; ++m)
            aF[m] = *(const bfrag*)&SM[cur * 2048 + (wr * 32 + m * 16 + l15) * 32 + lg * 8];
#pragma unroll
        for (int n = 0; n < 4; ++n)
            bF[n] = *(const bfrag*)&SM[4096 + cur * 4096 + (wc * 64 + n * 16 + l15) * 32 + lg * 8];
        __builtin_amdgcn_s_setprio(1);
#pragma unroll
        for (int m = 0; m < 2; ++m)
#pragma unroll
            for (int n = 0; n < 4; ++n)
                acc[m][n] = __builtin_amdgcn_mfma_f32_16x16x32_bf16(aF[m], bF[n], acc[m][n], 0, 0, 0);
        __builtin_amdgcn_s_setprio(0);
        if (kt < 31) {
            __syncthreads();
            cur ^= 1;
        }
    }

    __syncthreads();
#pragma unroll
    for (int m = 0; m < 2; ++m)
#pragma unroll
        for (int n = 0; n < 4; ++n) {
            const int lcol = wc * 64 + n * 16 + l15;
            const int gcol = bN * 128 + lcol;
            const float bv_ = bias[gcol];
#pragma unroll
            for (int j = 0; j < 4; ++j) {
                const int lrow = wr * 32 + m * 16 + lg * 4 + j;
                const float val = (acc[m][n][j] + bv_) * scale;
                const ushort hv = f2bf(val);
                Cout[(size_t)(bM * 64 + lrow) * 1024 + gcol] = hv;
                if (z) SM[lrow * 129 + lcol] = hv;
            }
        }

    if (z) {
        __syncthreads();
        const int b_ = (bM * 64) >> 11;
        const int s0 = (bM * 64) & 2047;
        const int h0 = bN * 2;
#pragma unroll
        for (int i = 0; i < 4; ++i) {
            const int c2 = i * 256 + tid;
            const int d128 = c2 >> 3;
            const int sb = (c2 & 7) * 8;
            union { ushort s[8]; v4u v; } tmp;
#pragma unroll
            for (int jj = 0; jj < 8; ++jj) {
                const int sl = sb + jj;
                const int js = (sl & ~15) | (sl & 3) | ((sl >> 1) & 4) | ((sl << 1) & 8);
                tmp.s[jj] = SM[js * 129 + d128];
            }
            ushort* dst = VPT + ((size_t)((b_ * 16 + h0 + (d128 >> 6)) * 64 + (d128 & 63))) * 2048 + s0 + sb;
            *(v4u*)dst = tmp.v;
        }
    }
}

// ---------------- combine4: AO = (sum Opart[s]) / (sum Lp[s]), bf16 ----------------
// streaming: 32MB read + 8MB write, 2048 blocks x 256 thr x 8 elems

__global__ __launch_bounds__(256) void combine4(
    const ushort* __restrict__ Op, const float* __restrict__ Lp, ushort* __restrict__ AO)
{
    const int t = blockIdx.x * 256 + threadIdx.x;
    const int e0 = t * 8;
    const int grow = e0 >> 10, col = e0 & 1023;
    const int b = grow >> 11, s = grow & 2047, h = col >> 6;
    const int li = (b * 16 + h) * 2048 + s;
    v4u r0 = *(const v4u*)(Op + e0);
    v4u r1 = *(const v4u*)(Op + 4194304 + e0);
    v4u r2 = *(const v4u*)(Op + 8388608 + e0);
    v4u r3 = *(const v4u*)(Op + 12582912 + e0);
    const float l = (Lp[li] + Lp[65536 + li]) + (Lp[131072 + li] + Lp[196608 + li]);
    const float inv = 1.0f / l;
    v4u o;
#pragma unroll
    for (int wd = 0; wd < 4; ++wd) {
        const float x0 = ((bf2f((ushort)(r0[wd] & 0xffff)) + bf2f((ushort)(r1[wd] & 0xffff)))
                        + (bf2f((ushort)(r2[wd] & 0xffff)) + bf2f((ushort)(r3[wd] & 0xffff)))) * inv;
        const float x1 = ((bf2f((ushort)(r0[wd] >> 16)) + bf2f((ushort)(r1[wd] >> 16)))
                        + (bf2f((ushort)(r2[wd] >> 16)) + bf2f((ushort)(r3[wd] >> 16)))) * inv;
        o[wd] = pack_bf16x2(x0, x1);
    }
    *(v4u*)(AO + e0) = o;
}

// ---------------- gemm_o_pre: out = AO @ WoT^T + bo (AO pre-normalized bf16) ----------------
// identical structure to gemm_qv (gld_lds A+B staging), fp32 out.

__global__ __launch_bounds__(256, 3) void gemm_o_pre(
    const ushort* __restrict__ A, const ushort* __restrict__ Bt,
    const float* __restrict__ bias, float* __restrict__ out)
{
    __shared__ ushort SM[12288];
    const int tid = threadIdx.x;
    const int lane = tid & 63, w = tid >> 6;
    const int l15 = lane & 15, lg = lane >> 4;
    const int wr = w >> 1, wc = w & 1;
    const int bM = blockIdx.y, bN = blockIdx.x;

    const ushort* Ag = A + (size_t)bM * 64 * 1024;
    const ushort* Bg = Bt + (size_t)bN * 128 * 1024;
    const int ar = tid >> 2;
    const int cc = (tid & 3) * 8;

    auto STAGE = [&](int buf, int kt) {
        const int kk = kt * 32;
        gld_lds16(Ag + (size_t)ar * 1024 + kk + cc, &SM[buf * 2048 + tid * 8]);
#pragma unroll
        for (int i = 0; i < 2; ++i)
            gld_lds16(Bg + (size_t)(ar + i * 64) * 1024 + kk + cc,
                      &SM[4096 + buf * 4096 + (tid + i * 256) * 8]);
    };

    f32x4 acc[2][4];
#pragma unroll
    for (int m = 0; m < 2; ++m)
#pragma unroll
        for (int n = 0; n < 4; ++n) acc[m][n] = (f32x4){0.f, 0.f, 0.f, 0.f};

    STAGE(0, 0);
    __syncthreads();
    int cur = 0;
    for (int kt = 0; kt < 32; ++kt) {
        if (kt < 31) STAGE(cur ^ 1, kt + 1);
        bfrag aF[2], bF[4];
#pragma unroll
        for (int m = 0; m < 2; ++m)
            aF[m] = *(const bfrag*)&SM[cur * 2048 + (wr * 32 + m * 16 + l15) * 32 + lg * 8];
#pragma unroll
        for (int n = 0; n < 4; ++n)
            bF[n] = *(const bfrag*)&SM[4096 + cur * 4096 + (wc * 64 + n * 16 + l15) * 32 + lg * 8];
        __builtin_amdgcn_s_setprio(1);
#pragma unroll
        for (int m = 0; m < 2; ++m)
#pragma unroll
            for (int n = 0; n < 4; ++n)
                acc[m][n] = __builtin_amdgcn_mfma_f32_16x16x32_bf16(aF[m], bF[n], acc[m][n], 0, 0, 0);
        __builtin_amdgcn_s_setprio(0);
        if (kt < 31) {
            __syncthreads();
            cur ^= 1;
        }
    }

#pragma unroll
    for (int m = 0; m < 2; ++m)
#pragma unroll
        for (int n = 0; n < 4; ++n) {
            const int gcol = bN * 128 + wc * 64 + n * 16 + l15;
            const float bv_ = bias[gcol];
#pragma unroll
            for (int j = 0; j < 4; ++j) {
                const int gr = bM * 64 + wr * 32 + m * 16 + lg * 4 + j;
                out[(size_t)gr * 1024 + gcol] = acc[m][n][j] + bv_;
            }
        }
}

// ---------------- gemm_o2: fused 2-way combine (proven small-ws path) ----------------

__global__ __launch_bounds__(256, 3) void gemm_o2(
    const ushort* __restrict__ Op, const float* __restrict__ Lp,
    const ushort* __restrict__ Bt, const float* __restrict__ bias,
    float* __restrict__ out)
{
    __shared__ ushort As[2][2048];
    __shared__ ushort Bs[2][4096];
    const int tid = threadIdx.x;
    const int lane = tid & 63, w = tid >> 6;
    const int l15 = lane & 15, lg = lane >> 4;
    const int wr = w >> 1, wc = w & 1;
    const int bM = blockIdx.y, bN = blockIdx.x;

    const ushort* Bg = Bt + (size_t)bN * 128 * 1024;
    const int ar = tid >> 2;
    const int cc = (tid & 3) * 8;
    const int grow = bM * 64 + ar;
    const int b_ = grow >> 11, s_ = grow & 2047;

    v4u aR, cR; float inv;
    auto LOAD_A = [&](int kt) {
        const int col = kt * 32 + cc;
        const int li = (b_ * 16 + (col >> 6)) * 2048 + s_;
        inv = 1.0f / (Lp[li] + Lp[65536 + li]);
        aR = *(const v4u*)(Op + (size_t)grow * 1024 + col);
        cR = *(const v4u*)(Op + 4194304 + (size_t)grow * 1024 + col);
    };
    auto WRITE_A = [&](int buf) {
        v4u o;
#pragma unroll
        for (int wd = 0; wd < 4; ++wd) {
            const float x0 = (bf2f((ushort)(aR[wd] & 0xffff)) + bf2f((ushort)(cR[wd] & 0xffff))) * inv;
            const float x1 = (bf2f((ushort)(aR[wd] >> 16))    + bf2f((ushort)(cR[wd] >> 16)))    * inv;
            o[wd] = pack_bf16x2(x0, x1);
        }
        *(v4u*)&As[buf][tid * 8] = o;
    };
    auto STAGE_B = [&](int buf, int kt) {
        const int kk = kt * 32;
#pragma unroll
        for (int i = 0; i < 2; ++i)
            gld_lds16(Bg + (size_t)(ar + i * 64) * 1024 + kk + cc, &Bs[buf][(tid + i * 256) * 8]);
    };

    f32x4 acc[2][4];
#pragma unroll
    for (int m = 0; m < 2; ++m)
#pragma unroll
        for (int n = 0; n < 4; ++n) acc[m][n] = (f32x4){0.f, 0.f, 0.f, 0.f};

    LOAD_A(0);
    STAGE_B(0, 0);
    WRITE_A(0);
    __syncthreads();
    int cur = 0;
    for (int kt = 0; kt < 32; ++kt) {
        if (kt < 31) {
            LOAD_A(kt + 1);
            STAGE_B(cur ^ 1, kt + 1);
        }
        bfrag aF[2], bF[4];
#pragma unroll
        for (int m = 0; m < 2; ++m) aF[m] = *(const bfrag*)&As[cur][(wr * 32 + m * 16 + l15) * 32 + lg * 8];
#pragma unroll
        for (int n = 0; n < 4; ++n) bF[n] = *(const bfrag*)&Bs[cur][(wc * 64 + n * 16 + l15) * 32 + lg * 8];
        __builtin_amdgcn_s_setprio(1);
#pragma unroll
        for (int m = 0; m < 2; ++m)
#pragma unroll
            for (int n = 0; n < 4; ++n)
                acc[m][n] = __builtin_amdgcn_mfma_f32_16x16x32_bf16(aF[m], bF[n], acc[m][n], 0, 0, 0);
        __builtin_amdgcn_s_setprio(0);
        if (kt < 31) {
            WRITE_A(cur ^ 1);
            __syncthreads();
            cur ^= 1;
        }
    }

#pragma unroll
    for (int m = 0; m < 2; ++m)
#pragma unroll
        for (int n = 0; n < 4; ++n) {
            const int gcol = bN * 128 + wc * 64 + n * 16 + l15;
            const float bv_ = bias[gcol];
#pragma unroll
            for (int j = 0; j < 4; ++j) {
                const int gr = bM * 64 + wr * 32 + m * 16 + lg * 4 + j;
                out[(size_t)gr * 1024 + gcol] = acc[m][n][j] + bv_;
            }
        }
}

// ---------------- flash attention<NT>: r16 structure, NT kv-tiles per block ----------------

template<int NT>
__global__ __launch_bounds__(256, 2) void attn_kernel(
    const ushort* __restrict__ QP, const ushort* __restrict__ VP,
    const ushort* __restrict__ VPT, ushort* __restrict__ Opart, float* __restrict__ Lpart)
{
    __shared__ ushort Ks[2][4096];
    __shared__ ushort Vs[2][4096];
    const int tid = threadIdx.x;
    const int w = tid >> 6, lane = tid & 63;
    const int l31 = lane & 31, hi = lane >> 5;
    const int bh = blockIdx.x, qt = blockIdx.y, half = blockIdx.z;
    const int b = bh >> 4, h = bh & 15;
    const int qrow0 = qt * 256 + w * 64;
    const int k0 = half * NT;

    const int sr = lane >> 3;
    const int sc = ((lane & 7) ^ sr) * 8;
    const ushort* Kg = VP + (size_t)(b * 2048) * 1024 + h * 64 + sc;
    const ushort* Vg = VPT + (size_t)bh * 131072 + sc;

    auto STAGE = [&](int slot, int kt) {
#pragma unroll
        for (int i = 0; i < 2; ++i) {
            const int kb = w * 2 + i;
            const int r = kb * 8 + sr;
            gld_lds16(Kg + (size_t)(kt * 64 + r) * 1024, &Ks[slot][kb * 512]);
            gld_lds16(Vg + (size_t)r * 2048 + kt * 64, &Vs[slot][kb * 512]);
        }
    };

    const ushort* Qp = QP + ((size_t)(b * 2048 + qrow0 + l31)) * 1024 + h * 64 + hi * 8;
    bfrag qA[4], qBt[4];
#pragma unroll
    for (int ds = 0; ds < 4; ++ds) {
        qA[ds]  = *(const bfrag*)(Qp + ds * 16);
        qBt[ds] = *(const bfrag*)(Qp + 32 * 1024 + ds * 16);
    }

    f32x16 OA0, OA1, OB0, OB1;
#pragma unroll
    for (int r = 0; r < 16; ++r) { OA0[r] = 0.f; OA1[r] = 0.f; OB0[r] = 0.f; OB1[r] = 0.f; }
    float lrunA = 0.f, lrunB = 0.f;

    const int swz = (l31 & 7) << 4;
    const int cA = hi * 16;

    STAGE(0, k0);
    __syncthreads();

    auto SOFTMAX = [&](f32x16& S0, f32x16& S1, bfrag (&pB)[4], float& lrun) {
        float p[32];
#pragma unroll
        for (int r = 0; r < 16; ++r) {
            p[r]      = __builtin_amdgcn_exp2f(S0[r]);
            p[16 + r] = __builtin_amdgcn_exp2f(S1[r]);
        }
        float s8[8];
#pragma unroll
        for (int i = 0; i < 8; ++i) s8[i] = (p[i] + p[i + 8]) + (p[i + 16] + p[i + 24]);
        lrun += ((s8[0] + s8[1]) + (s8[2] + s8[3])) + ((s8[4] + s8[5]) + (s8[6] + s8[7]));
#pragma unroll
        for (int c = 0; c < 4; ++c) {
            union { v4u u; bfrag f; } cv;
#pragma unroll
            for (int wd = 0; wd < 4; ++wd)
                cv.u[wd] = pack_bf16x2(p[8 * c + 2 * wd], p[8 * c + 2 * wd + 1]);
            pB[c] = cv.f;
        }
    };

#pragma unroll 1
    for (int t = 0; t < NT; ++t) {
        if (t > 0) __syncthreads();
        if (t + 1 < NT) STAGE((t + 1) & 1, k0 + t + 1);
        const ushort* Kb_ = Ks[t & 1];
        const ushort* Vb_ = Vs[t & 1];

        bfrag k0f[4], k1f[4];
#pragma unroll
        for (int ds = 0; ds < 4; ++ds) {
            k0f[ds] = *(const bfrag*)&Kb_[(l31 * 128 + ((ds * 32 + cA) ^ swz)) >> 1];
            k1f[ds] = *(const bfrag*)&Kb_[((l31 + 32) * 128 + ((ds * 32 + cA) ^ swz)) >> 1];
        }
        f32x16 SA0, SA1, SB0, SB1;
#pragma unroll
        for (int r = 0; r < 16; ++r) { SA0[r] = -16.f; SA1[r] = -16.f; SB0[r] = -16.f; SB1[r] = -16.f; }
        __builtin_amdgcn_s_setprio(1);
#pragma unroll
        for (int ds = 0; ds < 4; ++ds) {
            SA0 = mfma32(k0f[ds], qA[ds], SA0);
            SA1 = mfma32(k1f[ds], qA[ds], SA1);
            SB0 = mfma32(k0f[ds], qBt[ds], SB0);
            SB1 = mfma32(k1f[ds], qBt[ds], SB1);
        }
        __builtin_amdgcn_s_setprio(0);

        bfrag pBA[4], pBB[4];
        SOFTMAX(SA0, SA1, pBA, lrunA);
        SOFTMAX(SB0, SB1, pBB, lrunB);

        bfrag vF0[4], vF1[4];
#pragma unroll
        for (int c = 0; c < 4; ++c) {
            vF0[c] = *(const bfrag*)&Vb_[(l31 * 128 + ((c * 32 + cA) ^ swz)) >> 1];
            vF1[c] = *(const bfrag*)&Vb_[((l31 + 32) * 128 + ((c * 32 + cA) ^ swz)) >> 1];
        }
        __builtin_amdgcn_s_setprio(1);
#pragma unroll
        for (int c = 0; c < 4; ++c) {
            OA0 = mfma32(vF0[c], pBA[c], OA0);
            OA1 = mfma32(vF1[c], pBA[c], OA1);
            OB0 = mfma32(vF0[c], pBB[c], OB0);
            OB1 = mfma32(vF1[c], pBB[c], OB1);
        }
        __builtin_amdgcn_s_setprio(0);
    }

    lrunA += __shfl_xor(lrunA, 32);
    lrunB += __shfl_xor(lrunB, 32);
    ushort* AoA = Opart + (size_t)half * 4194304
                + (size_t)(b * 2048 + qrow0 + l31) * 1024 + h * 64 + hi * 4;
    ushort* AoB = AoA + 32 * 1024;
#pragma unroll
    for (int t = 0; t < 2; ++t) {
#pragma unroll
        for (int g = 0; g < 4; ++g) {
            const float a0 = t ? OA1[4 * g + 0] : OA0[4 * g + 0];
            const float a1 = t ? OA1[4 * g + 1] : OA0[4 * g + 1];
            const float a2 = t ? OA1[4 * g + 2] : OA0[4 * g + 2];
            const float a3 = t ? OA1[4 * g + 3] : OA0[4 * g + 3];
            *(v2u*)(AoA + t * 32 + g * 8) = (v2u){pack_bf16x2(a0, a1), pack_bf16x2(a2, a3)};
            const float b0 = t ? OB1[4 * g + 0] : OB0[4 * g + 0];
            const float b1 = t ? OB1[4 * g + 1] : OB0[4 * g + 1];
            const float b2 = t ? OB1[4 * g + 2] : OB0[4 * g + 2];
            const float b3 = t ? OB1[4 * g + 3] : OB0[4 * g + 3];
            *(v2u*)(AoB + t * 32 + g * 8) = (v2u){pack_bf16x2(b0, b1), pack_bf16x2(b2, b3)};
        }
    }
    if (hi == 0) {
        Lpart[half * 65536 + bh * 2048 + qrow0 + l31] = lrunA;
        Lpart[half * 65536 + bh * 2048 + qrow0 + 32 + l31] = lrunB;
    }
}

// ---------------- launcher ----------------

extern "C" void kernel_launch(void* const* d_in, const int* in_sizes, int n_in,
                              void* d_out, int out_size, void* d_ws, size_t ws_size,
                              hipStream_t stream) {
    (void)in_sizes; (void)n_in; (void)out_size;
    const float* q  = (const float*)d_in[0];
    const float* v  = (const float*)d_in[2];
    const float* Wq = (const float*)d_in[3];
    const float* bq = (const float*)d_in[4];
    const float* Wv = (const float*)d_in[7];
    const float* bv = (const float*)d_in[8];
    const float* Wo = (const float*)d_in[9];
    const float* bo = (const float*)d_in[10];
    float* out = (float*)d_out;
    char* ws = (char*)d_ws;
    const size_t MB = 1ull << 20;
    const bool big = ws_size >= 59 * MB;

    ushort* qbf = (ushort*)(ws + 0);
    ushort* vbf = (ushort*)(ws + 8 * MB);
    ushort* WqT = (ushort*)(ws + 16 * MB);
    ushort* WvT = (ushort*)(ws + 18 * MB);

    ushort *WoT, *QPb, *VPb, *VPT, *Opart; float* Lpart;
    if (big) {
        Opart = (ushort*)(ws + 0);           // 32MB
        Lpart = (float*)(ws + 32 * MB);      // 1MB
        WoT   = (ushort*)(ws + 33 * MB);     // 2MB
        QPb   = (ushort*)(ws + 35 * MB);     // 8MB (reused as AO after attn)
        VPb   = (ushort*)(ws + 43 * MB);     // 8MB
        VPT   = (ushort*)(ws + 51 * MB);     // 8MB
    } else {
        Opart = (ushort*)(ws + 0);           // 16MB
        Lpart = (float*)(ws + 16 * MB);
        WoT   = (ushort*)(ws + 20 * MB);
        QPb   = (ushort*)(ws + 22 * MB);
        VPb   = (ushort*)(ws + 30 * MB);
        VPT   = (ushort*)(ws + 38 * MB);
    }

    cvt_all<<<dim3(32, 32, 11), dim3(32, 8), 0, stream>>>(
        Wq, WqT, Wv, WvT, Wo, WoT, q, qbf, v, vbf);

    const float qscale = 0.125f * 1.44269504088896340736f;
    gemm_qv<<<dim3(8, 64, 2), 256, 0, stream>>>(qbf, WqT, bq, QPb,
                                                vbf, WvT, bv, VPb, VPT, qscale);
    if (big) {
        attn_kernel<8><<<dim3(32, 8, 4), 256, 0, stream>>>(QPb, VPb, VPT, Opart, Lpart);
        ushort* AO = QPb;                    // QPb dead after attn
        combine4<<<2048, 256, 0, stream>>>(Opart, Lpart, AO);
        gemm_o_pre<<<dim3(8, 64), 256, 0, stream>>>(AO, WoT, bo, out);
    } else {
        attn_kernel<16><<<dim3(32, 8, 2), 256, 0, stream>>>(QPb, VPb, VPT, Opart, Lpart);
        gemm_o2<<<dim3(8, 64), 256, 0, stream>>>(Opart, Lpart, WoT, bo, out);
    }
}

// Round 23
// 124.132 us; speedup vs baseline: 1.2682x; 1.0180x over previous
//
#include <hip/hip_runtime.h>
#include <hip/hip_bf16.h>

using bfrag  = __attribute__((ext_vector_type(8))) __bf16;
using f32x4  = __attribute__((ext_vector_type(4))) float;
using f32x16 = __attribute__((ext_vector_type(16))) float;
using v4u    = __attribute__((ext_vector_type(4))) unsigned int;
using v2u    = __attribute__((ext_vector_type(2))) unsigned int;

__device__ __forceinline__ ushort f2bf(float f) {
    union { float f; unsigned u; } c; c.f = f;
    return (ushort)((c.u + 0x7fffu + ((c.u >> 16) & 1u)) >> 16);
}

__device__ __forceinline__ float bf2f(ushort u) {
    union { unsigned u; float f; } c; c.u = (unsigned)u << 16; return c.f;
}

__device__ __forceinline__ unsigned pack_bf16x2(float lo, float hi) {
    union { __hip_bfloat162 h; unsigned u; } c;
    c.h = __float22bfloat162_rn(make_float2(lo, hi));   // lo -> low ushort, hi -> high
    return c.u;
}

__device__ __forceinline__ void gld_lds16(const ushort* g, ushort* l) {
    __builtin_amdgcn_global_load_lds(
        (const __attribute__((address_space(1))) void*)g,
        (__attribute__((address_space(3))) void*)l, 16, 0, 0);
}

__device__ __forceinline__ f32x16 mfma32(bfrag a, bfrag b, f32x16 c) {
    return __builtin_amdgcn_mfma_f32_32x32x16_bf16(a, b, c, 0, 0, 0);
}

// ---------------- conversions, one dispatch ----------------
// z = 0..2: fp32 [1024][1024] -> bf16 transposed (Wq, Wv, Wo)
// z = 3..10: q,v fp32 -> bf16 flat (2M float4 total)

__global__ void cvt_all(const float* __restrict__ s0, ushort* __restrict__ d0,
                        const float* __restrict__ s1, ushort* __restrict__ d1,
                        const float* __restrict__ s2, ushort* __restrict__ d2,
                        const float* __restrict__ q, ushort* __restrict__ qbf,
                        const float* __restrict__ v, ushort* __restrict__ vbf) {
    const int z = blockIdx.z;
    if (z < 3) {
        __shared__ float t[32][33];
        const float* src = z == 0 ? s0 : z == 1 ? s1 : s2;
        ushort* dst = z == 0 ? d0 : z == 1 ? d1 : d2;
        const int tx = threadIdx.x, ty = threadIdx.y;
        const int c0 = blockIdx.x * 32, r0 = blockIdx.y * 32;
        for (int i = ty; i < 32; i += 8) t[i][tx] = src[(size_t)(r0 + i) * 1024 + c0 + tx];
        __syncthreads();
        for (int i = ty; i < 32; i += 8) dst[(size_t)(c0 + i) * 1024 + r0 + tx] = f2bf(t[tx][i]);
    } else {
        const int tid = threadIdx.y * 32 + threadIdx.x;
        int i = ((z - 3) * 1024 + blockIdx.y * 32 + blockIdx.x) * 256 + tid;
        const float* s; ushort* d;
        if (i < 1048576) { s = q; d = qbf; } else { s = v; d = vbf; i -= 1048576; }
        float4 f = ((const float4*)s)[i];
        ((ushort4*)d)[i] = make_ushort4(f2bf(f.x), f2bf(f.y), f2bf(f.z), f2bf(f.w));
    }
}

// ---------------- gemm_qv: 64x128 tile, bf16 A via gld_lds, fused VPT epilogue ----------------

__global__ __launch_bounds__(256, 3) void gemm_qv(
    const ushort* __restrict__ Aq, const ushort* __restrict__ Wq, const float* __restrict__ bq, ushort* __restrict__ Cq,
    const ushort* __restrict__ Av, const ushort* __restrict__ Wv, const float* __restrict__ bv, ushort* __restrict__ Cv,
    ushort* __restrict__ VPT, float qscale)
{
    __shared__ ushort SM[12288];               // As[2] at 0/2048, Bs[2] at 4096/8192; reused as T[64][129]
    const int z = blockIdx.z;
    const ushort* A  = z ? Av : Aq;
    const ushort* Bt = z ? Wv : Wq;
    const float* bias = z ? bv : bq;
    ushort* Cout = z ? Cv : Cq;
    const float scale = z ? 1.0f : qscale;

    const int tid = threadIdx.x;
    const int lane = tid & 63, w = tid >> 6;
    const int l15 = lane & 15, lg = lane >> 4;
    const int wr = w >> 1, wc = w & 1;
    const int bM = blockIdx.y, bN = blockIdx.x;

    const ushort* Ag = A + (size_t)bM * 64 * 1024;
    const ushort* Bg = Bt + (size_t)bN * 128 * 1024;
    const int ar = tid >> 2;
    const int cc = (tid & 3) * 8;

    auto STAGE = [&](int buf, int kt) {
        const int kk = kt * 32;
        gld_lds16(Ag + (size_t)ar * 1024 + kk + cc, &SM[buf * 2048 + tid * 8]);
#pragma unroll
        for (int i = 0; i < 2; ++i)
            gld_lds16(Bg + (size_t)(ar + i * 64) * 1024 + kk + cc,
                      &SM[4096 + buf * 4096 + (tid + i * 256) * 8]);
    };

    f32x4 acc[2][4];
#pragma unroll
    for (int m = 0; m < 2; ++m)
#pragma unroll
        for (int n = 0; n < 4; ++n) acc[m][n] = (f32x4){0.f, 0.f, 0.f, 0.f};

    STAGE(0, 0);
    __syncthreads();
    int cur = 0;
    for (int kt = 0; kt < 32; ++kt) {
        if (kt < 31) STAGE(cur ^ 1, kt + 1);
        bfrag aF[2], bF[4];
#pragma unroll
        for (int m = 0; m < 2; ++m)
            aF[m] = *(const bfrag*)&SM[cur * 2048 + (wr * 32 + m * 16 + l15) * 32 + lg * 8];
#pragma unroll
        for (int n = 0; n < 4; ++n)
            bF[n] = *(const bfrag*)&SM[4096 + cur * 4096 + (wc * 64 + n * 16 + l15) * 32 + lg * 8];
        __builtin_amdgcn_s_setprio(1);
#pragma unroll
        for (int m = 0; m < 2; ++m)
#pragma unroll
            for (int n = 0; n < 4; ++n)
                acc[m][n] = __builtin_amdgcn_mfma_f32_16x16x32_bf16(aF[m], bF[n], acc[m][n], 0, 0, 0);
        __builtin_amdgcn_s_setprio(0);
        if (kt < 31) {
            __syncthreads();
            cur ^= 1;
        }
    }

    __syncthreads();                 // all waves done with LDS fragments; SM reusable as T
#pragma unroll
    for (int m = 0; m < 2; ++m)
#pragma unroll
        for (int n = 0; n < 4; ++n) {
            const int lcol = wc * 64 + n * 16 + l15;
            const int gcol = bN * 128 + lcol;
            const float bv_ = bias[gcol];
#pragma unroll
            for (int j = 0; j < 4; ++j) {
                const int lrow = wr * 32 + m * 16 + lg * 4 + j;
                const float val = (acc[m][n][j] + bv_) * scale;
                const ushort hv = f2bf(val);
                Cout[(size_t)(bM * 64 + lrow) * 1024 + gcol] = hv;
                if (z) SM[lrow * 129 + lcol] = hv;
            }
        }

    if (z) {                         // fused VPT transpose (sigma on s within 16-blocks)
        __syncthreads();
        const int b_ = (bM * 64) >> 11;
        const int s0 = (bM * 64) & 2047;
        const int h0 = bN * 2;
#pragma unroll
        for (int i = 0; i < 4; ++i) {
            const int c2 = i * 256 + tid;
            const int d128 = c2 >> 3;
            const int sb = (c2 & 7) * 8;
            union { ushort s[8]; v4u v; } tmp;
#pragma unroll
            for (int jj = 0; jj < 8; ++jj) {
                const int sl = sb + jj;
                const int js = (sl & ~15) | (sl & 3) | ((sl >> 1) & 4) | ((sl << 1) & 8);
                tmp.s[jj] = SM[js * 129 + d128];
            }
            ushort* dst = VPT + ((size_t)((b_ * 16 + h0 + (d128 >> 6)) * 64 + (d128 & 63))) * 2048 + s0 + sb;
            *(v4u*)dst = tmp.v;
        }
    }
}

// ---------------- gemm_o: out = normalize(Opart0+Opart1) @ WoT^T + bo (combine fused) ----------------

__global__ __launch_bounds__(256, 3) void gemm_o(
    const ushort* __restrict__ Op0, const ushort* __restrict__ Op1,
    const float* __restrict__ Lp,
    const ushort* __restrict__ Bt, const float* __restrict__ bias,
    float* __restrict__ out)
{
    __shared__ ushort As[2][2048];
    __shared__ ushort Bs[2][4096];
    const int tid = threadIdx.x;
    const int lane = tid & 63, w = tid >> 6;
    const int l15 = lane & 15, lg = lane >> 4;
    const int wr = w >> 1, wc = w & 1;
    const int bM = blockIdx.y, bN = blockIdx.x;

    const ushort* Bg = Bt + (size_t)bN * 128 * 1024;
    const int ar = tid >> 2;
    const int cc = (tid & 3) * 8;
    const int grow = bM * 64 + ar;
    const int b_ = grow >> 11, s_ = grow & 2047;

    v4u aR, cR; float inv;
    auto LOAD_A = [&](int kt) {
        const int col = kt * 32 + cc;
        const int li = (b_ * 16 + (col >> 6)) * 2048 + s_;
        inv = 1.0f / (Lp[li] + Lp[65536 + li]);
        aR = *(const v4u*)(Op0 + (size_t)grow * 1024 + col);
        cR = *(const v4u*)(Op1 + (size_t)grow * 1024 + col);
    };
    auto WRITE_A = [&](int buf) {
        v4u o;
#pragma unroll
        for (int wd = 0; wd < 4; ++wd) {
            const float x0 = (bf2f((ushort)(aR[wd] & 0xffff)) + bf2f((ushort)(cR[wd] & 0xffff))) * inv;
            const float x1 = (bf2f((ushort)(aR[wd] >> 16))    + bf2f((ushort)(cR[wd] >> 16)))    * inv;
            o[wd] = pack_bf16x2(x0, x1);
        }
        *(v4u*)&As[buf][tid * 8] = o;
    };
    auto STAGE_B = [&](int buf, int kt) {
        const int kk = kt * 32;
#pragma unroll
        for (int i = 0; i < 2; ++i)
            gld_lds16(Bg + (size_t)(ar + i * 64) * 1024 + kk + cc, &Bs[buf][(tid + i * 256) * 8]);
    };

    f32x4 acc[2][4];
#pragma unroll
    for (int m = 0; m < 2; ++m)
#pragma unroll
        for (int n = 0; n < 4; ++n) acc[m][n] = (f32x4){0.f, 0.f, 0.f, 0.f};

    LOAD_A(0);
    STAGE_B(0, 0);
    WRITE_A(0);
    __syncthreads();
    int cur = 0;
    for (int kt = 0; kt < 32; ++kt) {
        if (kt < 31) {
            LOAD_A(kt + 1);
            STAGE_B(cur ^ 1, kt + 1);
        }
        bfrag aF[2], bF[4];
#pragma unroll
        for (int m = 0; m < 2; ++m) aF[m] = *(const bfrag*)&As[cur][(wr * 32 + m * 16 + l15) * 32 + lg * 8];
#pragma unroll
        for (int n = 0; n < 4; ++n) bF[n] = *(const bfrag*)&Bs[cur][(wc * 64 + n * 16 + l15) * 32 + lg * 8];
        __builtin_amdgcn_s_setprio(1);
#pragma unroll
        for (int m = 0; m < 2; ++m)
#pragma unroll
            for (int n = 0; n < 4; ++n)
                acc[m][n] = __builtin_amdgcn_mfma_f32_16x16x32_bf16(aF[m], bF[n], acc[m][n], 0, 0, 0);
        __builtin_amdgcn_s_setprio(0);
        if (kt < 31) {
            WRITE_A(cur ^ 1);
            __syncthreads();
            cur ^= 1;
        }
    }

#pragma unroll
    for (int m = 0; m < 2; ++m)
#pragma unroll
        for (int n = 0; n < 4; ++n) {
            const int gcol = bN * 128 + wc * 64 + n * 16 + l15;
            const float bv_ = bias[gcol];
#pragma unroll
            for (int j = 0; j < 4; ++j) {
                const int gr = bM * 64 + wr * 32 + m * 16 + lg * 4 + j;
                out[(size_t)gr * 1024 + gcol] = acc[m][n][j] + bv_;
            }
        }
}

// ---------------- flash attention (r12/r16 structure, proven 52.7us) ----------------
// 4-wave blocks x 2/CU, q=64/wave, split-KV x2, fixed-offset softmax, VALU l-sum.
// Final form: all scheduling/packing/occupancy variants (r7,r13,r18,r19,r22) measured
// worse or neutral; this is the demonstrated 2-phase optimum (652 TF effective, D=64).

__global__ __launch_bounds__(256, 2) void attn_kernel(
    const ushort* __restrict__ QP, const ushort* __restrict__ VP,
    const ushort* __restrict__ VPT, ushort* __restrict__ Opart, float* __restrict__ Lpart)
{
    __shared__ ushort Ks[2][4096];
    __shared__ ushort Vs[2][4096];
    const int tid = threadIdx.x;
    const int w = tid >> 6, lane = tid & 63;
    const int l31 = lane & 31, hi = lane >> 5;
    const int bh = blockIdx.x, qt = blockIdx.y, half = blockIdx.z;
    const int b = bh >> 4, h = bh & 15;
    const int qrow0 = qt * 256 + w * 64;
    const int k0 = half * 16;

    const int sr = lane >> 3;
    const int sc = ((lane & 7) ^ sr) * 8;
    const ushort* Kg = VP + (size_t)(b * 2048) * 1024 + h * 64 + sc;
    const ushort* Vg = VPT + (size_t)bh * 131072 + sc;

    auto STAGE = [&](int slot, int kt) {
#pragma unroll
        for (int i = 0; i < 2; ++i) {
            const int kb = w * 2 + i;
            const int r = kb * 8 + sr;
            gld_lds16(Kg + (size_t)(kt * 64 + r) * 1024, &Ks[slot][kb * 512]);
            gld_lds16(Vg + (size_t)r * 2048 + kt * 64, &Vs[slot][kb * 512]);
        }
    };

    const ushort* Qp = QP + ((size_t)(b * 2048 + qrow0 + l31)) * 1024 + h * 64 + hi * 8;
    bfrag qA[4], qBt[4];
#pragma unroll
    for (int ds = 0; ds < 4; ++ds) {
        qA[ds]  = *(const bfrag*)(Qp + ds * 16);
        qBt[ds] = *(const bfrag*)(Qp + 32 * 1024 + ds * 16);
    }

    f32x16 OA0, OA1, OB0, OB1;
#pragma unroll
    for (int r = 0; r < 16; ++r) { OA0[r] = 0.f; OA1[r] = 0.f; OB0[r] = 0.f; OB1[r] = 0.f; }
    float lrunA = 0.f, lrunB = 0.f;

    const int swz = (l31 & 7) << 4;
    const int cA = hi * 16;

    STAGE(0, k0);
    __syncthreads();

    auto SOFTMAX = [&](f32x16& S0, f32x16& S1, bfrag (&pB)[4], float& lrun) {
        float p[32];
#pragma unroll
        for (int r = 0; r < 16; ++r) {
            p[r]      = __builtin_amdgcn_exp2f(S0[r]);
            p[16 + r] = __builtin_amdgcn_exp2f(S1[r]);
        }
        float s8[8];
#pragma unroll
        for (int i = 0; i < 8; ++i) s8[i] = (p[i] + p[i + 8]) + (p[i + 16] + p[i + 24]);
        lrun += ((s8[0] + s8[1]) + (s8[2] + s8[3])) + ((s8[4] + s8[5]) + (s8[6] + s8[7]));
#pragma unroll
        for (int c = 0; c < 4; ++c) {
            union { v4u u; bfrag f; } cv;
#pragma unroll
            for (int wd = 0; wd < 4; ++wd)
                cv.u[wd] = pack_bf16x2(p[8 * c + 2 * wd], p[8 * c + 2 * wd + 1]);
            pB[c] = cv.f;
        }
    };

#pragma unroll 1
    for (int t = 0; t < 16; ++t) {
        if (t > 0) __syncthreads();
        if (t + 1 < 16) STAGE((t + 1) & 1, k0 + t + 1);
        const ushort* Kb_ = Ks[t & 1];
        const ushort* Vb_ = Vs[t & 1];

        bfrag k0f[4], k1f[4];
#pragma unroll
        for (int ds = 0; ds < 4; ++ds) {
            k0f[ds] = *(const bfrag*)&Kb_[(l31 * 128 + ((ds * 32 + cA) ^ swz)) >> 1];
            k1f[ds] = *(const bfrag*)&Kb_[((l31 + 32) * 128 + ((ds * 32 + cA) ^ swz)) >> 1];
        }
        f32x16 SA0, SA1, SB0, SB1;
#pragma unroll
        for (int r = 0; r < 16; ++r) { SA0[r] = -16.f; SA1[r] = -16.f; SB0[r] = -16.f; SB1[r] = -16.f; }
        __builtin_amdgcn_s_setprio(1);
#pragma unroll
        for (int ds = 0; ds < 4; ++ds) {
            SA0 = mfma32(k0f[ds], qA[ds], SA0);
            SA1 = mfma32(k1f[ds], qA[ds], SA1);
            SB0 = mfma32(k0f[ds], qBt[ds], SB0);
            SB1 = mfma32(k1f[ds], qBt[ds], SB1);
        }
        __builtin_amdgcn_s_setprio(0);

        bfrag pBA[4], pBB[4];
        SOFTMAX(SA0, SA1, pBA, lrunA);
        SOFTMAX(SB0, SB1, pBB, lrunB);

        bfrag vF0[4], vF1[4];
#pragma unroll
        for (int c = 0; c < 4; ++c) {
            vF0[c] = *(const bfrag*)&Vb_[(l31 * 128 + ((c * 32 + cA) ^ swz)) >> 1];
            vF1[c] = *(const bfrag*)&Vb_[((l31 + 32) * 128 + ((c * 32 + cA) ^ swz)) >> 1];
        }
        __builtin_amdgcn_s_setprio(1);
#pragma unroll
        for (int c = 0; c < 4; ++c) {
            OA0 = mfma32(vF0[c], pBA[c], OA0);
            OA1 = mfma32(vF1[c], pBA[c], OA1);
            OB0 = mfma32(vF0[c], pBB[c], OB0);
            OB1 = mfma32(vF1[c], pBB[c], OB1);
        }
        __builtin_amdgcn_s_setprio(0);
    }

    lrunA += __shfl_xor(lrunA, 32);
    lrunB += __shfl_xor(lrunB, 32);
    ushort* AoA = Opart + (size_t)half * 4194304
                + (size_t)(b * 2048 + qrow0 + l31) * 1024 + h * 64 + hi * 4;
    ushort* AoB = AoA + 32 * 1024;
#pragma unroll
    for (int t = 0; t < 2; ++t) {
#pragma unroll
        for (int g = 0; g < 4; ++g) {
            const float a0 = t ? OA1[4 * g + 0] : OA0[4 * g + 0];
            const float a1 = t ? OA1[4 * g + 1] : OA0[4 * g + 1];
            const float a2 = t ? OA1[4 * g + 2] : OA0[4 * g + 2];
            const float a3 = t ? OA1[4 * g + 3] : OA0[4 * g + 3];
            *(v2u*)(AoA + t * 32 + g * 8) = (v2u){pack_bf16x2(a0, a1), pack_bf16x2(a2, a3)};
            const float b0 = t ? OB1[4 * g + 0] : OB0[4 * g + 0];
            const float b1 = t ? OB1[4 * g + 1] : OB0[4 * g + 1];
            const float b2 = t ? OB1[4 * g + 2] : OB0[4 * g + 2];
            const float b3 = t ? OB1[4 * g + 3] : OB0[4 * g + 3];
            *(v2u*)(AoB + t * 32 + g * 8) = (v2u){pack_bf16x2(b0, b1), pack_bf16x2(b2, b3)};
        }
    }
    if (hi == 0) {
        Lpart[half * 65536 + bh * 2048 + qrow0 + l31] = lrunA;
        Lpart[half * 65536 + bh * 2048 + qrow0 + 32 + l31] = lrunB;
    }
}

// ---------------- launcher ----------------

extern "C" void kernel_launch(void* const* d_in, const int* in_sizes, int n_in,
                              void* d_out, int out_size, void* d_ws, size_t ws_size,
                              hipStream_t stream) {
    (void)in_sizes; (void)n_in; (void)out_size; (void)ws_size;
    const float* q  = (const float*)d_in[0];
    const float* v  = (const float*)d_in[2];
    const float* Wq = (const float*)d_in[3];
    const float* bq = (const float*)d_in[4];
    const float* Wv = (const float*)d_in[7];
    const float* bv = (const float*)d_in[8];
    const float* Wo = (const float*)d_in[9];
    const float* bo = (const float*)d_in[10];
    float* out = (float*)d_out;
    char* ws = (char*)d_ws;
    const size_t MB = 1ull << 20;
    ushort* qbf = (ushort*)(ws + 0);         // 8MB (reused as Opart[0] after gemm_qv)
    ushort* vbf = (ushort*)(ws + 8 * MB);    // 8MB (reused as Opart[1] after gemm_qv)
    ushort* WqT = (ushort*)(ws + 16 * MB);   // 2MB (Lpart overlays after gemm_qv)
    ushort* WvT = (ushort*)(ws + 18 * MB);   // 2MB
    ushort* WoT = (ushort*)(ws + 20 * MB);   // 2MB (read by gemm_o)
    ushort* QPb = (ushort*)(ws + 22 * MB);   // 8MB
    ushort* VPb = (ushort*)(ws + 30 * MB);   // 8MB
    ushort* VPT = (ushort*)(ws + 38 * MB);   // 8MB

    ushort* Opart = (ushort*)(ws + 0);       // [2][4096][1024] bf16
    float*  Lpart = (float*)(ws + 16 * MB);  // [2][32][2048] f32

    cvt_all<<<dim3(32, 32, 11), dim3(32, 8), 0, stream>>>(
        Wq, WqT, Wv, WvT, Wo, WoT, q, qbf, v, vbf);

    const float qscale = 0.125f * 1.44269504088896340736f;
    gemm_qv<<<dim3(8, 64, 2), 256, 0, stream>>>(qbf, WqT, bq, QPb,
                                                vbf, WvT, bv, VPb, VPT, qscale);
    attn_kernel<<<dim3(32, 8, 2), 256, 0, stream>>>(QPb, VPb, VPT, Opart, Lpart);
    gemm_o<<<dim3(8, 64), 256, 0, stream>>>(Opart, Opart + 4194304, Lpart, WoT, bo, out);
}